// Round 6
// baseline (143.695 us; speedup 1.0000x reference)
//
#include <hip/hip_runtime.h>
#include <hip/hip_bf16.h>

// MultiPropMLP on MI355X: N=1M samples, MLP 16->64->64->1, per-sample weight
// set k in [0,8) via idxs (fp32 buffers, values bf16-rounded).
// Round 6: fused sort+gather+MLP per 512-sample span.
//  - X loaded COALESCED in original order into LDS (row-major, A-frag-ready);
//    MLP indirects via sId (LDS) instead of random HBM gathers.
//  - b0 folded into W0B at K-slot 16 (A supplies 1.0 at q==2,j==0).
//  - layer 1 -> layer 2 fused in registers: relu+dot via VALU, 4x shfl_xor
//    reduce (no second LDS round-trip, no W2 MFMA fragments).
//  - H1 pack via v_cvt_pk_bf16_f32 (__float22bfloat162_rn).

typedef __attribute__((ext_vector_type(8))) short bfrag;   // 8 bf16 (4 VGPRs)
typedef __attribute__((ext_vector_type(4))) float ffrag;   // 4 fp32 acc

#define SPAN        512
#define NSPANS      2048
#define IMG_STRIDE  13312     // W0B 4096 | W1B 8192 | f32: b1[64] W2[64] b2
#define WS_NEED     ((size_t)(8 * IMG_STRIDE))

__device__ __forceinline__ unsigned short bf16r(float f) {
    unsigned int u = __float_as_uint(f);
    u += 0x7fffu + ((u >> 16) & 1u);
    return (unsigned short)(u >> 16);
}
// pack two fp32 (already exact bf16) -> u32 via byte-perm (truncation exact)
__device__ __forceinline__ unsigned int pack_trunc(float hiF, float loF) {
    return __builtin_amdgcn_perm(__float_as_uint(hiF), __float_as_uint(loF), 0x07060302u);
}
// packed RNE f32x2 -> bf16x2 (v_cvt_pk_bf16_f32)
__device__ __forceinline__ unsigned int pack_cvt(float loF, float hiF) {
    union { __hip_bfloat162 h2; unsigned int u; } c;
    c.h2 = __float22bfloat162_rn(make_float2(loF, hiF));
    return c.u;
}

// ---------- K0: per-k weight images (MFMA B-fragment order) ----------
// W0B @0    : [4 nt][64 lane][8 j] bf16, k-slot kk=q*8+j: W0 rows for kk<16,
//             b0 at kk==16 (bias dim), zero above.
// W1B @4096 : [4 nt][2 s][64 lane][8 j] bf16, permuted k: h=(j&3)*16+s*8+q*2+(j>>2)
// floats @12288: b1[64] | W2[64] | b2
__global__ void k_build_images(const float* __restrict__ W0, const float* __restrict__ b0,
                               const float* __restrict__ W1, const float* __restrict__ b1,
                               const float* __restrict__ W2, const float* __restrict__ b2,
                               unsigned char* __restrict__ wsB) {
    const int k = blockIdx.x, t = threadIdx.x;
    unsigned char* img = wsB + k * IMG_STRIDE;
    unsigned short* w0b = (unsigned short*)img;
    unsigned short* w1b = (unsigned short*)(img + 4096);
    float* bias = (float*)(img + 12288);
    for (int e = t; e < 2048; e += 256) {
        int j = e & 7, lane = (e >> 3) & 63, nt = e >> 9, q = lane >> 4;
        int kk = q * 8 + j, n = nt * 16 + (lane & 15);
        unsigned short v = 0;
        if (kk < 16) v = bf16r(W0[k * 1024 + kk * 64 + n]);
        else if (kk == 16) v = bf16r(b0[k * 64 + n]);   // bias dim (A carries 1.0)
        w0b[e] = v;
    }
    for (int e = t; e < 4096; e += 256) {
        int j = e & 7, lane = (e >> 3) & 63, s = (e >> 9) & 1, nt = e >> 10, q = lane >> 4;
        int h = (j & 3) * 16 + s * 8 + q * 2 + (j >> 2);
        w1b[e] = bf16r(W1[k * 4096 + h * 64 + nt * 16 + (lane & 15)]);
    }
    if (t < 64) bias[t] = b1[k * 64 + t];
    else if (t < 128) bias[t] = W2[k * 64 + (t - 64)];
    else if (t == 128) bias[128] = b2[k];
}

// ---------- K1: fused sort + coalesced stage + MFMA MLP ----------
__global__ __launch_bounds__(256, 4) void k_fused(const int* __restrict__ idxs,
                                                  const float* __restrict__ xs,
                                                  const unsigned char* __restrict__ wsB,
                                                  float* __restrict__ out) {
    __shared__ int wcnt[2][4][8];
    __shared__ int bsbase[2][4][8];
    __shared__ int cntS[8], startS[8];
    __shared__ unsigned short sId[SPAN];                       // 1 KB
    __shared__ __align__(16) unsigned short Xg[SPAN * 16];     // 16 KB row-major
    __shared__ __align__(16) unsigned short H3[4][16 * 72];    // 9 KB (per wave)
    __shared__ float outBuf[SPAN];                             // 2 KB

    const int tid = threadIdx.x, lane = tid & 63, w = tid >> 6;
    const int q = lane >> 4, l15 = lane & 15;
    const int base = blockIdx.x * SPAN;

    // ---- issue X loads early (coalesced, original order): rows tid, tid+256
    const float4* xp0 = (const float4*)(xs + (size_t)(base + tid) * 16);
    const float4* xp1 = (const float4*)(xs + (size_t)(base + 256 + tid) * 16);
    float4 g0 = xp0[0], g1 = xp0[1], g2 = xp0[2], g3 = xp0[3];
    float4 g4 = xp1[0], g5 = xp1[1], g6 = xp1[2], g7 = xp1[3];

    // ---- phase S: block-local counting sort (ballot ranks, stable) ----
    int kreg[2], lrank[2];
    #pragma unroll
    for (int it = 0; it < 2; ++it) {
        int k = idxs[base + it * 256 + tid];
        kreg[it] = k;
        unsigned long long mymask = 0;
        #pragma unroll
        for (int kk = 0; kk < 8; ++kk) {
            unsigned long long m = __ballot(k == kk);
            if (k == kk) mymask = m;
            if (lane == 0) wcnt[it][w][kk] = (int)__popcll(m);
        }
        lrank[it] = (int)__popcll(mymask & ((1ull << lane) - 1ull));
    }
    __syncthreads();
    if (tid < 8) {
        int c = 0;
        for (int it = 0; it < 2; ++it)
            for (int w2 = 0; w2 < 4; ++w2) c += wcnt[it][w2][tid];
        cntS[tid] = c;
    }
    __syncthreads();
    if (tid == 0) {
        int s = 0;
        for (int k = 0; k < 8; ++k) { startS[k] = s; s += cntS[k]; }
    }
    __syncthreads();
    if (tid < 64) {
        int it = tid >> 5, w2 = (tid >> 3) & 3, kk = tid & 7;
        int b = startS[kk];
        for (int it2 = 0; it2 < it; ++it2)
            for (int w3 = 0; w3 < 4; ++w3) b += wcnt[it2][w3][kk];
        for (int w3 = 0; w3 < w2; ++w3) b += wcnt[it][w3][kk];
        bsbase[it][w2][kk] = b;
    }
    __syncthreads();
    #pragma unroll
    for (int it = 0; it < 2; ++it)
        sId[bsbase[it][w][kreg[it]] + lrank[it]] = (unsigned short)(it * 256 + tid);

    // ---- phase G: pack staged rows (exact trunc), row-major LDS ----
    {
        uint4 lo, hi;
        lo.x = pack_trunc(g0.y, g0.x); lo.y = pack_trunc(g0.w, g0.z);
        lo.z = pack_trunc(g1.y, g1.x); lo.w = pack_trunc(g1.w, g1.z);
        hi.x = pack_trunc(g2.y, g2.x); hi.y = pack_trunc(g2.w, g2.z);
        hi.z = pack_trunc(g3.y, g3.x); hi.w = pack_trunc(g3.w, g3.z);
        *(uint4*)(Xg + tid * 16) = lo;
        *(uint4*)(Xg + tid * 16 + 8) = hi;
        lo.x = pack_trunc(g4.y, g4.x); lo.y = pack_trunc(g4.w, g4.z);
        lo.z = pack_trunc(g5.y, g5.x); lo.w = pack_trunc(g5.w, g5.z);
        hi.x = pack_trunc(g6.y, g6.x); hi.y = pack_trunc(g6.w, g6.z);
        hi.z = pack_trunc(g7.y, g7.x); hi.w = pack_trunc(g7.w, g7.z);
        *(uint4*)(Xg + (256 + tid) * 16) = lo;
        *(uint4*)(Xg + (256 + tid) * 16 + 8) = hi;
    }
    __syncthreads();

    // ---- phase M: wave w processes buckets k = w, w+4 ----
    unsigned short* H = H3[w];
    #pragma unroll
    for (int kk2 = 0; kk2 < 2; ++kk2) {
        const int k = w + kk2 * 4;
        const int cnt = cntS[k];
        if (cnt == 0) continue;
        const int start = startS[k];
        const unsigned char* img = wsB + k * IMG_STRIDE;

        bfrag w0f[4], w1f[4][2];
        #pragma unroll
        for (int nt = 0; nt < 4; ++nt)
            w0f[nt] = *(const bfrag*)(img + nt * 1024 + lane * 16);
        #pragma unroll
        for (int nt = 0; nt < 4; ++nt)
            #pragma unroll
            for (int s = 0; s < 2; ++s)
                w1f[nt][s] = *(const bfrag*)(img + 4096 + ((nt * 2 + s) * 64 + lane) * 16);
        const float* bias = (const float*)(img + 12288);
        float b1v[4], w2v[4];
        #pragma unroll
        for (int nt = 0; nt < 4; ++nt) {
            b1v[nt] = bias[nt * 16 + l15];
            w2v[nt] = bias[64 + nt * 16 + l15];
        }
        const float b2v = bias[128];

        const int nst = (cnt + 15) >> 4;

        // A loader: indirect row via sId, read Xg row-major; q==2 carries the
        // bias dim 1.0 at k-slot 16.
        auto loadA = [&](int st, bfrag* a, int* rowid) {
            int R = start + st * 16 + l15;
            int Rm = start + cnt - 1;
            R = R < Rm ? R : Rm;
            int row = (int)sId[R];
            *rowid = row;
            bfrag av = {0, 0, 0, 0, 0, 0, 0, 0};
            if (q < 2)
                av = *(const bfrag*)(Xg + row * 16 + q * 8);
            else if (q == 2)
                av[0] = (short)0x3F80;   // bf16 1.0
            *a = av;
        };

        bfrag aCur;
        int rowCur;
        loadA(0, &aCur, &rowCur);

        for (int st = 0; st < nst; ++st) {
            // ---- layer 0 (+b0 via bias dim): 4 x mfma 16x16x32 ----
            ffrag acc0[4];
            #pragma unroll
            for (int nt = 0; nt < 4; ++nt) {
                ffrag z = {0.f, 0.f, 0.f, 0.f};
                acc0[nt] = __builtin_amdgcn_mfma_f32_16x16x32_bf16(aCur, w0f[nt], z, 0, 0, 0);
            }
            bfrag aNxt = {0, 0, 0, 0, 0, 0, 0, 0};
            int rowNxt = 0;
            if (st + 1 < nst) loadA(st + 1, &aNxt, &rowNxt);

            // ---- H1 = relu(acc0) -> LDS (permuted slots, packed cvt) ----
            #pragma unroll
            for (int r = 0; r < 4; ++r) {
                float v0 = acc0[0][r]; v0 = v0 > 0.f ? v0 : 0.f;
                float v1 = acc0[1][r]; v1 = v1 > 0.f ? v1 : 0.f;
                float v2 = acc0[2][r]; v2 = v2 > 0.f ? v2 : 0.f;
                float v3 = acc0[3][r]; v3 = v3 > 0.f ? v3 : 0.f;
                uint2 u;
                u.x = pack_cvt(v0, v1);
                u.y = pack_cvt(v2, v3);
                *(uint2*)((unsigned char*)H + (q * 4 + r) * 144 + l15 * 8) = u;
            }

            // ---- layer 1: 8 x mfma over permuted H slots ----
            bfrag a10 = *(const bfrag*)((unsigned char*)H + l15 * 144 + q * 16);
            bfrag a11 = *(const bfrag*)((unsigned char*)H + l15 * 144 + 64 + q * 16);
            ffrag acc1[4];
            #pragma unroll
            for (int nt = 0; nt < 4; ++nt) {
                ffrag z = {0.f, 0.f, 0.f, 0.f};
                acc1[nt] = __builtin_amdgcn_mfma_f32_16x16x32_bf16(a10, w1f[nt][0], z, 0, 0, 0);
                acc1[nt] = __builtin_amdgcn_mfma_f32_16x16x32_bf16(a11, w1f[nt][1], acc1[nt], 0, 0, 0);
            }

            // ---- layer 2 fused in regs: relu(acc1+b1).W2, shfl-reduce ----
            #pragma unroll
            for (int r = 0; r < 4; ++r) {
                float p = 0.f;
                #pragma unroll
                for (int nt = 0; nt < 4; ++nt) {
                    float h = acc1[nt][r] + b1v[nt];
                    h = h > 0.f ? h : 0.f;
                    p = fmaf(h, w2v[nt], p);
                }
                p += __shfl_xor(p, 1);
                p += __shfl_xor(p, 2);
                p += __shfl_xor(p, 4);
                p += __shfl_xor(p, 8);
                // lane with l15 == row-in-subtile owns that row's id (rowCur)
                if (l15 == q * 4 + r && st * 16 + l15 < cnt)
                    outBuf[rowCur] = p + b2v;
            }

            aCur = aNxt;
            rowCur = rowNxt;
        }
    }
    __syncthreads();

    // ---- phase O: coalesced out write (512 floats) ----
    ((float2*)(out + base))[tid] = ((const float2*)outBuf)[tid];
}

// ---------- fallback: per-thread fp32 ----------
__global__ void k_fallback(const int* __restrict__ idxs, const float* __restrict__ xs,
                           const float* __restrict__ W0, const float* __restrict__ b0,
                           const float* __restrict__ W1, const float* __restrict__ b1,
                           const float* __restrict__ W2, const float* __restrict__ b2,
                           float* __restrict__ out, int N) {
    int n = blockIdx.x * blockDim.x + threadIdx.x;
    if (n >= N) return;
    int k = idxs[n];
    float h0[64];
    #pragma unroll
    for (int j = 0; j < 64; ++j) h0[j] = b0[k * 64 + j];
    for (int i = 0; i < 16; ++i) {
        float xi = xs[(size_t)n * 16 + i];
        #pragma unroll
        for (int j = 0; j < 64; ++j) h0[j] = fmaf(xi, W0[k * 1024 + i * 64 + j], h0[j]);
    }
    #pragma unroll
    for (int j = 0; j < 64; ++j) h0[j] = fmaxf(h0[j], 0.f);
    float acc = b2[k];
    for (int jc = 0; jc < 4; ++jc) {
        float h1[16];
        #pragma unroll
        for (int j = 0; j < 16; ++j) h1[j] = b1[k * 64 + jc * 16 + j];
        for (int i = 0; i < 64; ++i) {
            float hv = h0[i];
            #pragma unroll
            for (int j = 0; j < 16; ++j)
                h1[j] = fmaf(hv, W1[k * 4096 + i * 64 + jc * 16 + j], h1[j]);
        }
        #pragma unroll
        for (int j = 0; j < 16; ++j) acc = fmaf(fmaxf(h1[j], 0.f), W2[k * 64 + jc * 16 + j], acc);
    }
    out[n] = acc;
}

extern "C" void kernel_launch(void* const* d_in, const int* in_sizes, int n_in,
                              void* d_out, int out_size, void* d_ws, size_t ws_size,
                              hipStream_t stream) {
    const int*   idxs = (const int*)d_in[0];
    const float* xs   = (const float*)d_in[1];
    const float* W0   = (const float*)d_in[2];
    const float* b0   = (const float*)d_in[3];
    const float* W1   = (const float*)d_in[4];
    const float* b1   = (const float*)d_in[5];
    const float* W2   = (const float*)d_in[6];
    const float* b2   = (const float*)d_in[7];
    float* out = (float*)d_out;
    const int N = in_sizes[0];  // 1,048,576

    if (N != SPAN * NSPANS || ws_size < WS_NEED) {
        k_fallback<<<(N + 255) / 256, 256, 0, stream>>>(idxs, xs, W0, b0, W1, b1, W2, b2, out, N);
        return;
    }

    unsigned char* wsB = (unsigned char*)d_ws;
    k_build_images<<<8, 256, 0, stream>>>(W0, b0, W1, b1, W2, b2, wsB);
    k_fused<<<NSPANS, 256, 0, stream>>>(idxs, xs, wsB, out);
}